// Round 1
// baseline (830.213 us; speedup 1.0000x reference)
//
#include <hip/hip_runtime.h>

#define HH 1024
#define VV 50257
#define LL 64
#define BB 512

typedef __bf16 bf16;
typedef bf16 bf16x8 __attribute__((ext_vector_type(8)));
typedef bf16 bf16x4 __attribute__((ext_vector_type(4)));
typedef float f32x4 __attribute__((ext_vector_type(4)));

static __device__ __forceinline__ bf16 f2bf(float f) {
  unsigned u = __builtin_bit_cast(unsigned, f);
  unsigned r = u + 0x7fffu + ((u >> 16) & 1u);
  unsigned short h = (unsigned short)(r >> 16);
  return __builtin_bit_cast(bf16, h);
}

// Convert emb -> A_cat[:, 0:1024] bf16, h0 -> h0b bf16
__global__ void k_convert(const float* __restrict__ emb, const float* __restrict__ h0,
                          bf16* __restrict__ A_cat, bf16* __restrict__ h0b) {
  int i = blockIdx.x * 256 + threadIdx.x;  // < B*H
  int b = i >> 10, h = i & 1023;
  A_cat[(size_t)b * 2048 + h] = f2bf(emb[i]);
  h0b[i] = f2bf(h0[i]);
}

// Per-batch-row: attention scores, softmax, attn_applied (fp32 math).
// Writes attn_weights (f32, d_out region 3) and attn_applied bf16 into A_cat[:,1024:2048].
__global__ void k_attn(const float* __restrict__ emb, const float* __restrict__ h0,
                       const float* __restrict__ enc,
                       const float* __restrict__ attn_W, const float* __restrict__ attn_b,
                       float* __restrict__ attn_out, bf16* __restrict__ A_cat) {
  int b = blockIdx.x;
  int t = threadIdx.x;
  __shared__ float red[256];
  __shared__ float w[LL];
  int l = t & 63, part = t >> 6;
  const float* cemb = emb + (size_t)b * HH;
  const float* ch0  = h0  + (size_t)b * HH;
  float acc = 0.f;
  for (int k = part * 512; k < part * 512 + 512; ++k) {
    float c = (k < HH) ? cemb[k] : ch0[k - HH];
    acc += c * attn_W[(size_t)k * LL + l];
  }
  red[t] = acc;
  __syncthreads();
  if (t < 64) {
    float s = red[t] + red[t + 64] + red[t + 128] + red[t + 192] + attn_b[t];
    float m = s;
    for (int off = 32; off; off >>= 1) m = fmaxf(m, __shfl_xor(m, off));
    float e = __expf(s - m);
    float sum = e;
    for (int off = 32; off; off >>= 1) sum += __shfl_xor(sum, off);
    float wl = e / sum;
    w[t] = wl;
    attn_out[(size_t)b * LL + t] = wl;
  }
  __syncthreads();
  for (int h = t; h < HH; h += 256) {
    float a = 0.f;
    for (int ll = 0; ll < LL; ++ll) a += w[ll] * enc[(size_t)ll * HH + h];
    A_cat[(size_t)b * 2048 + HH + h] = f2bf(a);
  }
}

// Generic MFMA GEMM: C = A(MxK bf16, k-contig) * B + bias
// BLAYOUT 0: B is fp32 KxN, n-contiguous (comb_W, out_W) -> transpose+convert in staging
// BLAYOUT 1: B is fp32 NxK, k-contiguous (W_ih, W_hh)    -> convert in staging
// OMODE 0: f32 out; 1: bf16 relu out; 2: bf16 out
template <int BLAYOUT, int OMODE>
__global__ __launch_bounds__(256) void k_gemm64(const bf16* __restrict__ A,
                                                const float* __restrict__ Bm,
                                                const float* __restrict__ bias,
                                                void* __restrict__ Cout,
                                                int M, int N, int K) {
  const int m0 = blockIdx.x * 64;   // m-tiles innermost for L2 reuse of W panel
  const int n0 = blockIdx.y * 64;
  const int t = threadIdx.x;
  __shared__ bf16 As[64][40];
  __shared__ bf16 Bs[64][40];
  const int wave = t >> 6, lane = t & 63;
  const int wr = (wave >> 1) * 32, wc = (wave & 1) * 32;
  const int lg = lane >> 4, lr = lane & 15;
  f32x4 acc[2][2] = {{{0.f,0.f,0.f,0.f},{0.f,0.f,0.f,0.f}},
                     {{0.f,0.f,0.f,0.f},{0.f,0.f,0.f,0.f}}};

  for (int k0 = 0; k0 < K; k0 += 32) {
    __syncthreads();
    {
      const int r = t >> 2, kq = (t & 3) << 3;
      const bf16* src = A + (size_t)(m0 + r) * K + k0 + kq;
      *(bf16x8*)(&As[r][kq]) = *(const bf16x8*)src;
    }
    if (BLAYOUT == 0) {
#pragma unroll
      for (int i = 0; i < 2; ++i) {
        const int q = t * 2 + i;
        const int k = q >> 4, n4 = (q & 15) << 2;
        const float* src = Bm + (size_t)(k0 + k) * N + (n0 + n4);
        float v0 = 0.f, v1 = 0.f, v2 = 0.f, v3 = 0.f;
        if (n0 + n4 + 3 < N) {
          v0 = src[0]; v1 = src[1]; v2 = src[2]; v3 = src[3];
        } else {
          if (n0 + n4 + 0 < N) v0 = src[0];
          if (n0 + n4 + 1 < N) v1 = src[1];
          if (n0 + n4 + 2 < N) v2 = src[2];
          if (n0 + n4 + 3 < N) v3 = src[3];
        }
        Bs[n4 + 0][k] = f2bf(v0);
        Bs[n4 + 1][k] = f2bf(v1);
        Bs[n4 + 2][k] = f2bf(v2);
        Bs[n4 + 3][k] = f2bf(v3);
      }
    } else {
#pragma unroll
      for (int i = 0; i < 2; ++i) {
        const int q = t * 2 + i;
        const int n = q >> 3, kq = (q & 7) << 2;
        float4 v = make_float4(0.f, 0.f, 0.f, 0.f);
        if (n0 + n < N) v = *(const float4*)(Bm + (size_t)(n0 + n) * K + k0 + kq);
        bf16x4 w;
        w[0] = f2bf(v.x); w[1] = f2bf(v.y); w[2] = f2bf(v.z); w[3] = f2bf(v.w);
        *(bf16x4*)(&Bs[n][kq]) = w;
      }
    }
    __syncthreads();
    const int kq = lg << 3;
    bf16x8 a0 = *(const bf16x8*)(&As[wr + lr][kq]);
    bf16x8 a1 = *(const bf16x8*)(&As[wr + 16 + lr][kq]);
    bf16x8 b0 = *(const bf16x8*)(&Bs[wc + lr][kq]);
    bf16x8 b1 = *(const bf16x8*)(&Bs[wc + 16 + lr][kq]);
    acc[0][0] = __builtin_amdgcn_mfma_f32_16x16x32_bf16(a0, b0, acc[0][0], 0, 0, 0);
    acc[0][1] = __builtin_amdgcn_mfma_f32_16x16x32_bf16(a0, b1, acc[0][1], 0, 0, 0);
    acc[1][0] = __builtin_amdgcn_mfma_f32_16x16x32_bf16(a1, b0, acc[1][0], 0, 0, 0);
    acc[1][1] = __builtin_amdgcn_mfma_f32_16x16x32_bf16(a1, b1, acc[1][1], 0, 0, 0);
  }

#pragma unroll
  for (int i = 0; i < 2; ++i)
#pragma unroll
    for (int j = 0; j < 2; ++j)
#pragma unroll
      for (int r = 0; r < 4; ++r) {
        const int row = m0 + wr + 16 * i + lg * 4 + r;
        const int col = n0 + wc + 16 * j + lr;
        if (col < N) {
          float vv = acc[i][j][r] + bias[col];
          if (OMODE == 0)
            ((float*)Cout)[(size_t)row * N + col] = vv;
          else if (OMODE == 1)
            ((bf16*)Cout)[(size_t)row * N + col] = f2bf(fmaxf(vv, 0.f));
          else
            ((bf16*)Cout)[(size_t)row * N + col] = f2bf(vv);
        }
      }
}

__global__ void k_gru(const float* __restrict__ gi, const float* __restrict__ gh,
                      const float* __restrict__ h0,
                      float* __restrict__ h1_out, bf16* __restrict__ h1b) {
  int i = blockIdx.x * 256 + threadIdx.x;  // B*H
  int b = i >> 10, h = i & 1023;
  size_t base = (size_t)b * 3072;
  float ir = gi[base + h], iz = gi[base + 1024 + h], in_ = gi[base + 2048 + h];
  float hr = gh[base + h], hz = gh[base + 1024 + h], hn = gh[base + 2048 + h];
  float r = 1.f / (1.f + __expf(-(ir + hr)));
  float z = 1.f / (1.f + __expf(-(iz + hz)));
  float n = tanhf(in_ + r * hn);
  float h1 = (1.f - z) * n + z * h0[i];
  h1_out[i] = h1;
  h1b[i] = f2bf(h1);
}

__global__ void k_logsoftmax(const bf16* __restrict__ z, float* __restrict__ out) {
  int b = blockIdx.x;
  int t = threadIdx.x;  // 256
  const bf16* zr = z + (size_t)b * VV;
  float m = -INFINITY, s = 0.f;
  for (int v = t; v < VV; v += 256) {
    float x = (float)zr[v];
    float nm = fmaxf(m, x);
    s = s * __expf(m - nm) + __expf(x - nm);
    m = nm;
  }
  for (int off = 32; off; off >>= 1) {
    float mo = __shfl_xor(m, off), so = __shfl_xor(s, off);
    float nm = fmaxf(m, mo);
    s = s * __expf(m - nm) + so * __expf(mo - nm);
    m = nm;
  }
  __shared__ float ms[4], ss[4];
  if ((t & 63) == 0) { ms[t >> 6] = m; ss[t >> 6] = s; }
  __syncthreads();
  if (t == 0) {
    float M = ms[0], S = ss[0];
    for (int wv = 1; wv < 4; ++wv) {
      float nm = fmaxf(M, ms[wv]);
      S = S * __expf(M - nm) + ss[wv] * __expf(ms[wv] - nm);
      M = nm;
    }
    ss[0] = logf(S) + M;  // lse
  }
  __syncthreads();
  float lse = ss[0];
  float* orow = out + (size_t)b * VV;
  for (int v = t; v < VV; v += 256) orow[v] = (float)zr[v] - lse;
}

extern "C" void kernel_launch(void* const* d_in, const int* in_sizes, int n_in,
                              void* d_out, int out_size, void* d_ws, size_t ws_size,
                              hipStream_t stream) {
  const float* emb    = (const float*)d_in[0];
  const float* h0     = (const float*)d_in[1];
  const float* enc    = (const float*)d_in[2];
  const float* attn_W = (const float*)d_in[3];
  const float* attn_b = (const float*)d_in[4];
  const float* comb_W = (const float*)d_in[5];
  const float* comb_b = (const float*)d_in[6];
  const float* W_ih   = (const float*)d_in[7];
  const float* W_hh   = (const float*)d_in[8];
  const float* b_ih   = (const float*)d_in[9];
  const float* b_hh   = (const float*)d_in[10];
  const float* out_W  = (const float*)d_in[11];
  const float* out_b  = (const float*)d_in[12];

  float* out      = (float*)d_out;                 // B*V
  float* h1out    = out + (size_t)BB * VV;         // B*H
  float* attn_out = h1out + (size_t)BB * HH;       // B*L

  char* ws = (char*)d_ws;
  bf16* A_cat = (bf16*)(ws);                       // 512 x 2048 bf16 (2 MB)
  bf16* h0b   = (bf16*)(ws + 2097152);             // 1 MB
  bf16* x     = (bf16*)(ws + 3145728);             // 1 MB
  bf16* h1b   = (bf16*)(ws + 4194304);             // 1 MB
  float* gi   = (float*)(ws + 5242880);            // 6.29 MB
  float* gh   = (float*)(ws + 11534336);           // 6.29 MB
  bf16* z     = (bf16*)(ws + 17825792);            // 51.5 MB

  k_convert<<<BB * HH / 256, 256, 0, stream>>>(emb, h0, A_cat, h0b);
  k_attn<<<BB, 256, 0, stream>>>(emb, h0, enc, attn_W, attn_b, attn_out, A_cat);
  k_gemm64<0, 1><<<dim3(8, 16), 256, 0, stream>>>(A_cat, comb_W, comb_b, x, BB, HH, 2 * HH);
  k_gemm64<1, 0><<<dim3(8, 48), 256, 0, stream>>>(x, W_ih, b_ih, gi, BB, 3 * HH, HH);
  k_gemm64<1, 0><<<dim3(8, 48), 256, 0, stream>>>(h0b, W_hh, b_hh, gh, BB, 3 * HH, HH);
  k_gru<<<BB * HH / 256, 256, 0, stream>>>(gi, gh, h0, h1out, h1b);
  k_gemm64<0, 2><<<dim3(8, (VV + 63) / 64), 256, 0, stream>>>(h1b, out_W, out_b, z, BB, VV, HH);
  k_logsoftmax<<<BB, 256, 0, stream>>>(z, out);
}

// Round 2
// 724.502 us; speedup vs baseline: 1.1459x; 1.1459x over previous
//
#include <hip/hip_runtime.h>

#define HH 1024
#define VV 50257
#define ZS 50264   // padded z row stride (mult of 8 -> 16B aligned rows)
#define LL 64
#define BB 512

typedef __bf16 bf16;
typedef bf16 bf16x8 __attribute__((ext_vector_type(8)));
typedef float f32x4 __attribute__((ext_vector_type(4)));
typedef unsigned uint4v __attribute__((ext_vector_type(4)));

static __device__ __forceinline__ bf16 f2bf(float f) {
  unsigned u = __builtin_bit_cast(unsigned, f);
  unsigned r = u + 0x7fffu + ((u >> 16) & 1u);
  unsigned short h = (unsigned short)(r >> 16);
  return __builtin_bit_cast(bf16, h);
}

static __device__ __forceinline__ unsigned cvt_pk(float lo, float hi) {
  unsigned r;
  asm("v_cvt_pk_bf16_f32 %0, %1, %2" : "=v"(r) : "v"(lo), "v"(hi));
  return r;
}

// ---------- convert: emb -> A_cat[:,0:1024], h0 -> h0b ----------
__global__ void k_convert(const float* __restrict__ emb, const float* __restrict__ h0,
                          bf16* __restrict__ A_cat, bf16* __restrict__ h0b) {
  int i = blockIdx.x * 256 + threadIdx.x;  // < B*H
  int b = i >> 10, h = i & 1023;
  A_cat[(size_t)b * 2048 + h] = f2bf(emb[i]);
  h0b[i] = f2bf(h0[i]);
}

// ---------- attention (unchanged from passing round 1) ----------
__global__ void k_attn(const float* __restrict__ emb, const float* __restrict__ h0,
                       const float* __restrict__ enc,
                       const float* __restrict__ attn_W, const float* __restrict__ attn_b,
                       float* __restrict__ attn_out, bf16* __restrict__ A_cat) {
  int b = blockIdx.x;
  int t = threadIdx.x;
  __shared__ float red[256];
  __shared__ float w[LL];
  int l = t & 63, part = t >> 6;
  const float* cemb = emb + (size_t)b * HH;
  const float* ch0  = h0  + (size_t)b * HH;
  float acc = 0.f;
  for (int k = part * 512; k < part * 512 + 512; ++k) {
    float c = (k < HH) ? cemb[k] : ch0[k - HH];
    acc += c * attn_W[(size_t)k * LL + l];
  }
  red[t] = acc;
  __syncthreads();
  if (t < 64) {
    float s = red[t] + red[t + 64] + red[t + 128] + red[t + 192] + attn_b[t];
    float m = s;
    for (int off = 32; off; off >>= 1) m = fmaxf(m, __shfl_xor(m, off));
    float e = __expf(s - m);
    float sum = e;
    for (int off = 32; off; off >>= 1) sum += __shfl_xor(sum, off);
    float wl = e / sum;
    w[t] = wl;
    attn_out[(size_t)b * LL + t] = wl;
  }
  __syncthreads();
  for (int h = t; h < HH; h += 256) {
    float a = 0.f;
    for (int ll = 0; ll < LL; ++ll) a += w[ll] * enc[(size_t)ll * HH + h];
    A_cat[(size_t)b * 2048 + HH + h] = f2bf(a);
  }
}

// ---------- generic GEMM: C(512 x N) = A(512 x K bf16) * B + bias ----------
// BM=256, BN=64, BK=32; 256 threads (4 waves, each 64m x 64n).
// BLAYOUT 0: B fp32 KxN n-contig (comb_W, out_W); BLAYOUT 1: B fp32 NxK k-contig.
// OMODE 0: f32; 1: bf16 relu; 2: bf16.
// A-operand read directly from global (A <= 1MB, L2-resident), 1-iter reg prefetch.
// B staged to LDS bf16 [64][40] (conflict-free b128 writes), double-buffered, 1 barrier/iter.
template <int BLAYOUT, int OMODE>
__global__ __launch_bounds__(256, 3) void k_gemm(
    const bf16* __restrict__ A, const float* __restrict__ Bm,
    const float* __restrict__ bias, void* __restrict__ Cout,
    int N, int K, int ldc) {
  __shared__ __align__(16) unsigned short Bs[2][64][40];
  const int t = threadIdx.x;
  const int nwg = gridDim.x;
  const int bid = blockIdx.x;
  // bijective XCD-chunked swizzle (m204): consecutive work -> same XCD
  const int xcd = bid & 7, jj = bid >> 3;
  const int q = nwg >> 3, r = nwg & 7;
  const int w = (xcd < r ? xcd * (q + 1) : r * (q + 1) + (xcd - r) * q) + jj;
  const int n0 = (w >> 1) * 64;   // m-innermost: the 2 m-blocks of a panel are adjacent
  const int m0 = (w & 1) * 256;
  const int lane = t & 63, wv = t >> 6;
  const int lg = lane >> 4, lr = lane & 15;

  const bf16* Ap = A + (size_t)(m0 + wv * 64 + lr) * K + lg * 8;

  // staging indices
  const int sn0 = (BLAYOUT == 0) ? (t & 63) : (t >> 2);        // n within tile
  const int sk0 = (BLAYOUT == 0) ? ((t >> 6) * 8) : ((t & 3) * 8);  // k8 within tile

  f32x4 acc[4][4] = {};
  bf16x8 a[4], an[4];
#pragma unroll
  for (int i = 0; i < 4; ++i) a[i] = *(const bf16x8*)(Ap + (size_t)i * 16 * K);

  const int nk = K >> 5;
  int cur = 0;

  // stage k-tile 0 into buf 0
  {
    const int k0 = 0;
    if (BLAYOUT == 0) {
      const bool nok = (n0 + sn0) < N;
      const float* bsrc = Bm + (size_t)(k0 + sk0) * N + n0 + sn0;
      float v[8];
#pragma unroll
      for (int e = 0; e < 8; ++e) v[e] = nok ? bsrc[(size_t)e * N] : 0.f;
      uint4v p = {cvt_pk(v[0], v[1]), cvt_pk(v[2], v[3]), cvt_pk(v[4], v[5]), cvt_pk(v[6], v[7])};
      *(uint4v*)(&Bs[0][sn0][sk0]) = p;
    } else {
      const float* bsrc = Bm + (size_t)(n0 + sn0) * K + k0 + sk0;
      float4 f0 = *(const float4*)(bsrc);
      float4 f1 = *(const float4*)(bsrc + 4);
      uint4v p = {cvt_pk(f0.x, f0.y), cvt_pk(f0.z, f0.w), cvt_pk(f1.x, f1.y), cvt_pk(f1.z, f1.w)};
      *(uint4v*)(&Bs[0][sn0][sk0]) = p;
    }
  }

  for (int ik = 0; ik < nk; ++ik) {
    __syncthreads();
    const bool more = (ik + 1 < nk);
    if (more) {
      const int k0 = (ik + 1) * 32;
      if (BLAYOUT == 0) {
        const bool nok = (n0 + sn0) < N;
        const float* bsrc = Bm + (size_t)(k0 + sk0) * N + n0 + sn0;
        float v[8];
#pragma unroll
        for (int e = 0; e < 8; ++e) v[e] = nok ? bsrc[(size_t)e * N] : 0.f;
        uint4v p = {cvt_pk(v[0], v[1]), cvt_pk(v[2], v[3]), cvt_pk(v[4], v[5]), cvt_pk(v[6], v[7])};
        *(uint4v*)(&Bs[cur ^ 1][sn0][sk0]) = p;
      } else {
        const float* bsrc = Bm + (size_t)(n0 + sn0) * K + k0 + sk0;
        float4 f0 = *(const float4*)(bsrc);
        float4 f1 = *(const float4*)(bsrc + 4);
        uint4v p = {cvt_pk(f0.x, f0.y), cvt_pk(f0.z, f0.w), cvt_pk(f1.x, f1.y), cvt_pk(f1.z, f1.w)};
        *(uint4v*)(&Bs[cur ^ 1][sn0][sk0]) = p;
      }
#pragma unroll
      for (int i = 0; i < 4; ++i)
        an[i] = *(const bf16x8*)(Ap + (size_t)i * 16 * K + (ik + 1) * 32);
    }
    bf16x8 b[4];
#pragma unroll
    for (int jx = 0; jx < 4; ++jx)
      b[jx] = *(const bf16x8*)(&Bs[cur][jx * 16 + lr][lg * 8]);
#pragma unroll
    for (int i = 0; i < 4; ++i)
#pragma unroll
      for (int jx = 0; jx < 4; ++jx)
        acc[i][jx] = __builtin_amdgcn_mfma_f32_16x16x32_bf16(a[i], b[jx], acc[i][jx], 0, 0, 0);
    if (more) {
#pragma unroll
      for (int i = 0; i < 4; ++i) a[i] = an[i];
    }
    cur ^= 1;
  }

  // epilogue
  float bb[4];
#pragma unroll
  for (int jx = 0; jx < 4; ++jx) {
    int col = n0 + 16 * jx + lr;
    bb[jx] = (col < N) ? bias[col] : 0.f;
  }
#pragma unroll
  for (int i = 0; i < 4; ++i)
#pragma unroll
    for (int jx = 0; jx < 4; ++jx) {
      const int col = n0 + 16 * jx + lr;
      if (col < N) {
#pragma unroll
        for (int rr = 0; rr < 4; ++rr) {
          const int row = m0 + wv * 64 + 16 * i + lg * 4 + rr;
          float vvv = acc[i][jx][rr] + bb[jx];
          if (OMODE == 0)
            ((float*)Cout)[(size_t)row * ldc + col] = vvv;
          else if (OMODE == 1)
            ((bf16*)Cout)[(size_t)row * ldc + col] = f2bf(fmaxf(vvv, 0.f));
          else
            ((bf16*)Cout)[(size_t)row * ldc + col] = f2bf(vvv);
        }
      }
    }
}

// ---------- GRU elementwise ----------
__global__ void k_gru(const float* __restrict__ gi, const float* __restrict__ gh,
                      const float* __restrict__ h0,
                      float* __restrict__ h1_out, bf16* __restrict__ h1b) {
  int i = blockIdx.x * 256 + threadIdx.x;  // B*H
  int b = i >> 10, h = i & 1023;
  size_t base = (size_t)b * 3072;
  float ir = gi[base + h], iz = gi[base + 1024 + h], in_ = gi[base + 2048 + h];
  float hr = gh[base + h], hz = gh[base + 1024 + h], hn = gh[base + 2048 + h];
  float r = 1.f / (1.f + __expf(-(ir + hr)));
  float z = 1.f / (1.f + __expf(-(iz + hz)));
  float n = tanhf(in_ + r * hn);
  float h1 = (1.f - z) * n + z * h0[i];
  h1_out[i] = h1;
  h1b[i] = f2bf(h1);
}

// ---------- log-softmax over padded z rows ----------
__global__ __launch_bounds__(512) void k_lsm(const bf16* __restrict__ z, float* __restrict__ out) {
  const int b = blockIdx.x, t = threadIdx.x;
  const bf16* zr = z + (size_t)b * ZS;
  float m = -1e30f, s = 0.f;
  // 6282 full bf16x8 chunks cover cols 0..50255; col 50256 handled by t==0
  for (int c = t; c < 6282; c += 512) {
    bf16x8 v = *(const bf16x8*)(zr + (size_t)c * 8);
#pragma unroll
    for (int e = 0; e < 8; ++e) {
      float x = (float)v[e];
      float nm = fmaxf(m, x);
      s = s * __expf(m - nm) + __expf(x - nm);
      m = nm;
    }
  }
  if (t == 0) {
    float x = (float)zr[VV - 1];
    float nm = fmaxf(m, x);
    s = s * __expf(m - nm) + __expf(x - nm);
    m = nm;
  }
  for (int off = 32; off; off >>= 1) {
    float mo = __shfl_xor(m, off), so = __shfl_xor(s, off);
    float nm = fmaxf(m, mo);
    s = s * __expf(m - nm) + so * __expf(mo - nm);
    m = nm;
  }
  __shared__ float ms[8], ss[8];
  if ((t & 63) == 0) { ms[t >> 6] = m; ss[t >> 6] = s; }
  __syncthreads();
  if (t == 0) {
    float M = ms[0], S = ss[0];
    for (int wv = 1; wv < 8; ++wv) {
      float nm = fmaxf(M, ms[wv]);
      S = S * __expf(M - nm) + ss[wv] * __expf(ms[wv] - nm);
      M = nm;
    }
    ss[0] = logf(S) + M;  // lse
  }
  __syncthreads();
  const float lse = ss[0];
  float* orow = out + (size_t)b * VV;
  for (int v = t; v < VV; v += 512) orow[v] = (float)zr[v] - lse;
}

extern "C" void kernel_launch(void* const* d_in, const int* in_sizes, int n_in,
                              void* d_out, int out_size, void* d_ws, size_t ws_size,
                              hipStream_t stream) {
  const float* emb    = (const float*)d_in[0];
  const float* h0     = (const float*)d_in[1];
  const float* enc    = (const float*)d_in[2];
  const float* attn_W = (const float*)d_in[3];
  const float* attn_b = (const float*)d_in[4];
  const float* comb_W = (const float*)d_in[5];
  const float* comb_b = (const float*)d_in[6];
  const float* W_ih   = (const float*)d_in[7];
  const float* W_hh   = (const float*)d_in[8];
  const float* b_ih   = (const float*)d_in[9];
  const float* b_hh   = (const float*)d_in[10];
  const float* out_W  = (const float*)d_in[11];
  const float* out_b  = (const float*)d_in[12];

  float* out      = (float*)d_out;                 // B*V
  float* h1out    = out + (size_t)BB * VV;         // B*H
  float* attn_out = h1out + (size_t)BB * HH;       // B*L

  char* ws = (char*)d_ws;
  bf16* A_cat = (bf16*)(ws);                       // 512 x 2048
  bf16* h0b   = (bf16*)(ws + 2097152);
  bf16* x     = (bf16*)(ws + 3145728);
  bf16* h1b   = (bf16*)(ws + 4194304);
  float* gi   = (float*)(ws + 5242880);
  float* gh   = (float*)(ws + 11534336);
  bf16* z     = (bf16*)(ws + 17825792);            // 512 x ZS

  k_convert<<<BB * HH / 256, 256, 0, stream>>>(emb, h0, A_cat, h0b);
  k_attn<<<BB, 256, 0, stream>>>(emb, h0, enc, attn_W, attn_b, attn_out, A_cat);
  k_gemm<0, 1><<<32, 256, 0, stream>>>(A_cat, comb_W, comb_b, x, HH, 2 * HH, HH);
  k_gemm<1, 0><<<96, 256, 0, stream>>>(x, W_ih, b_ih, gi, 3 * HH, HH, 3 * HH);
  k_gemm<1, 0><<<96, 256, 0, stream>>>(h0b, W_hh, b_hh, gh, 3 * HH, HH, 3 * HH);
  k_gru<<<BB * HH / 256, 256, 0, stream>>>(gi, gh, h0, h1out, h1b);
  k_gemm<0, 2><<<2 * ((VV + 63) / 64), 256, 0, stream>>>(h1b, out_W, out_b, z, VV, HH, ZS);
  k_lsm<<<BB, 512, 0, stream>>>(z, out);
}

// Round 3
// 497.750 us; speedup vs baseline: 1.6679x; 1.4556x over previous
//
#include <hip/hip_runtime.h>

#define HH 1024
#define VV 50257
#define ZS 50264   // padded z row stride (mult of 8 -> 16B aligned rows)
#define LL 64
#define BB 512

typedef __bf16 bf16;
typedef bf16 bf16x8 __attribute__((ext_vector_type(8)));
typedef float f32x4 __attribute__((ext_vector_type(4)));
typedef unsigned uint4v __attribute__((ext_vector_type(4)));

static __device__ __forceinline__ bf16 f2bf(float f) {
  unsigned u = __builtin_bit_cast(unsigned, f);
  unsigned r = u + 0x7fffu + ((u >> 16) & 1u);
  unsigned short h = (unsigned short)(r >> 16);
  return __builtin_bit_cast(bf16, h);
}

static __device__ __forceinline__ unsigned cvt_pk(float lo, float hi) {
  unsigned r;
  asm("v_cvt_pk_bf16_f32 %0, %1, %2" : "=v"(r) : "v"(lo), "v"(hi));
  return r;
}

// ---------- convert: emb -> A_cat[:,0:1024]; emb,h0 -> cat2 ----------
__global__ void k_convert(const float* __restrict__ emb, const float* __restrict__ h0,
                          bf16* __restrict__ A_cat, bf16* __restrict__ cat2) {
  int i = blockIdx.x * 256 + threadIdx.x;  // < B*H
  int b = i >> 10, h = i & 1023;
  bf16 e = f2bf(emb[i]);
  A_cat[(size_t)b * 2048 + h] = e;
  cat2[(size_t)b * 2048 + h] = e;
  cat2[(size_t)b * 2048 + 1024 + h] = f2bf(h0[i]);
}

// ---------- generic GEMM: C(512 x N) = A(512 x K bf16, row stride lda) * B + bias ----------
// BM=256, BN=64, BK=32; 256 threads (4 waves, each 64m x 64n).
// BLAYOUT 0: B fp32 KxN n-contig; BLAYOUT 1: B fp32 NxK k-contig (row stride = K; no k-split).
// OMODE 0: f32; 1: bf16 relu; 2: bf16.
// blockIdx.y = k-chunk (split-K): A col offset kb*K, B row offset kb*K, C offset kb*BB*ldc.
template <int BLAYOUT, int OMODE>
__global__ __launch_bounds__(256, 3) void k_gemm(
    const bf16* __restrict__ A, const float* __restrict__ Bm,
    const float* __restrict__ bias, void* __restrict__ Cout,
    int N, int K, int ldc, int lda) {
  __shared__ __align__(16) unsigned short Bs[2][64][40];
  const int t = threadIdx.x;
  const int nwg = gridDim.x;
  const int bid = blockIdx.x;
  const int kb = blockIdx.y;
  // bijective XCD-chunked swizzle (m204)
  const int xcd = bid & 7, jj = bid >> 3;
  const int q = nwg >> 3, r = nwg & 7;
  const int w = (xcd < r ? xcd * (q + 1) : r * (q + 1) + (xcd - r) * q) + jj;
  const int n0 = (w >> 1) * 64;   // m-innermost: the 2 m-blocks of a panel are adjacent
  const int m0 = (w & 1) * 256;
  const int lane = t & 63, wv = t >> 6;
  const int lg = lane >> 4, lr = lane & 15;

  const bf16* Ap = A + (size_t)(m0 + wv * 64 + lr) * lda + (size_t)kb * K + lg * 8;
  const float* Bk = Bm + (BLAYOUT == 0 ? (size_t)kb * K * N : (size_t)0);

  // staging indices
  const int sn0 = (BLAYOUT == 0) ? (t & 63) : (t >> 2);
  const int sk0 = (BLAYOUT == 0) ? ((t >> 6) * 8) : ((t & 3) * 8);

  f32x4 acc[4][4] = {};
  bf16x8 a[4], an[4];
#pragma unroll
  for (int i = 0; i < 4; ++i) a[i] = *(const bf16x8*)(Ap + (size_t)i * 16 * lda);

  const int nk = K >> 5;
  int cur = 0;

  {
    if (BLAYOUT == 0) {
      const bool nok = (n0 + sn0) < N;
      const float* bsrc = Bk + (size_t)sk0 * N + n0 + sn0;
      float v[8];
#pragma unroll
      for (int e = 0; e < 8; ++e) v[e] = nok ? bsrc[(size_t)e * N] : 0.f;
      uint4v p = {cvt_pk(v[0], v[1]), cvt_pk(v[2], v[3]), cvt_pk(v[4], v[5]), cvt_pk(v[6], v[7])};
      *(uint4v*)(&Bs[0][sn0][sk0]) = p;
    } else {
      const float* bsrc = Bk + (size_t)(n0 + sn0) * K + sk0;
      float4 f0 = *(const float4*)(bsrc);
      float4 f1 = *(const float4*)(bsrc + 4);
      uint4v p = {cvt_pk(f0.x, f0.y), cvt_pk(f0.z, f0.w), cvt_pk(f1.x, f1.y), cvt_pk(f1.z, f1.w)};
      *(uint4v*)(&Bs[0][sn0][sk0]) = p;
    }
  }

  for (int ik = 0; ik < nk; ++ik) {
    __syncthreads();
    const bool more = (ik + 1 < nk);
    if (more) {
      const int k0 = (ik + 1) * 32;
      if (BLAYOUT == 0) {
        const bool nok = (n0 + sn0) < N;
        const float* bsrc = Bk + (size_t)(k0 + sk0) * N + n0 + sn0;
        float v[8];
#pragma unroll
        for (int e = 0; e < 8; ++e) v[e] = nok ? bsrc[(size_t)e * N] : 0.f;
        uint4v p = {cvt_pk(v[0], v[1]), cvt_pk(v[2], v[3]), cvt_pk(v[4], v[5]), cvt_pk(v[6], v[7])};
        *(uint4v*)(&Bs[cur ^ 1][sn0][sk0]) = p;
      } else {
        const float* bsrc = Bk + (size_t)(n0 + sn0) * K + k0 + sk0;
        float4 f0 = *(const float4*)(bsrc);
        float4 f1 = *(const float4*)(bsrc + 4);
        uint4v p = {cvt_pk(f0.x, f0.y), cvt_pk(f0.z, f0.w), cvt_pk(f1.x, f1.y), cvt_pk(f1.z, f1.w)};
        *(uint4v*)(&Bs[cur ^ 1][sn0][sk0]) = p;
      }
#pragma unroll
      for (int i = 0; i < 4; ++i)
        an[i] = *(const bf16x8*)(Ap + (size_t)i * 16 * lda + (ik + 1) * 32);
    }
    bf16x8 b[4];
#pragma unroll
    for (int jx = 0; jx < 4; ++jx)
      b[jx] = *(const bf16x8*)(&Bs[cur][jx * 16 + lr][lg * 8]);
#pragma unroll
    for (int i = 0; i < 4; ++i)
#pragma unroll
      for (int jx = 0; jx < 4; ++jx)
        acc[i][jx] = __builtin_amdgcn_mfma_f32_16x16x32_bf16(a[i], b[jx], acc[i][jx], 0, 0, 0);
    if (more) {
#pragma unroll
      for (int i = 0; i < 4; ++i) a[i] = an[i];
    }
    cur ^= 1;
  }

  // epilogue
  float bb[4];
#pragma unroll
  for (int jx = 0; jx < 4; ++jx) {
    int col = n0 + 16 * jx + lr;
    bb[jx] = (bias && col < N) ? bias[col] : 0.f;
  }
  float* co_f = (float*)Cout + (size_t)kb * BB * ldc;
  bf16* co_b = (bf16*)Cout;
#pragma unroll
  for (int i = 0; i < 4; ++i)
#pragma unroll
    for (int jx = 0; jx < 4; ++jx) {
      const int col = n0 + 16 * jx + lr;
      if (col < N) {
#pragma unroll
        for (int rr = 0; rr < 4; ++rr) {
          const int row = m0 + wv * 64 + 16 * i + lg * 4 + rr;
          float vvv = acc[i][jx][rr] + bb[jx];
          if (OMODE == 0)
            co_f[(size_t)row * ldc + col] = vvv;
          else if (OMODE == 1)
            co_b[(size_t)row * ldc + col] = f2bf(fmaxf(vvv, 0.f));
          else
            co_b[(size_t)row * ldc + col] = f2bf(vvv);
        }
      }
    }
}

// ---------- softmax over 64 scores/row (sums 4 split-K partials) ----------
__global__ __launch_bounds__(256) void k_smax(const float* __restrict__ sp,
                                              const float* __restrict__ attn_b,
                                              float* __restrict__ attn_out,
                                              bf16* __restrict__ aw_b) {
  const int t = threadIdx.x;
  const int row = blockIdx.x * 4 + (t >> 6);
  const int l = t & 63;
  const size_t idx = (size_t)row * LL + l;
  float s = sp[idx] + sp[idx + (size_t)BB * LL] + sp[idx + (size_t)2 * BB * LL] +
            sp[idx + (size_t)3 * BB * LL] + attn_b[l];
  float m = s;
#pragma unroll
  for (int off = 32; off; off >>= 1) m = fmaxf(m, __shfl_xor(m, off));
  float e = __expf(s - m);
  float sum = e;
#pragma unroll
  for (int off = 32; off; off >>= 1) sum += __shfl_xor(sum, off);
  float wv = e / sum;
  attn_out[idx] = wv;
  aw_b[idx] = f2bf(wv);
}

// ---------- GRU elementwise ----------
__global__ void k_gru(const float* __restrict__ gi, const float* __restrict__ gh,
                      const float* __restrict__ h0,
                      float* __restrict__ h1_out, bf16* __restrict__ h1b) {
  int i = blockIdx.x * 256 + threadIdx.x;  // B*H
  int b = i >> 10, h = i & 1023;
  size_t base = (size_t)b * 3072;
  float ir = gi[base + h], iz = gi[base + 1024 + h], in_ = gi[base + 2048 + h];
  float hr = gh[base + h], hz = gh[base + 1024 + h], hn = gh[base + 2048 + h];
  float r = 1.f / (1.f + __expf(-(ir + hr)));
  float z = 1.f / (1.f + __expf(-(iz + hz)));
  float n = tanhf(in_ + r * hn);
  float h1 = (1.f - z) * n + z * h0[i];
  h1_out[i] = h1;
  h1b[i] = f2bf(h1);
}

// ---------- log-softmax over padded z rows ----------
__global__ __launch_bounds__(512) void k_lsm(const bf16* __restrict__ z, float* __restrict__ out) {
  const int b = blockIdx.x, t = threadIdx.x;
  const bf16* zr = z + (size_t)b * ZS;
  float m = -1e30f, s = 0.f;
  for (int c = t; c < 6282; c += 512) {
    bf16x8 v = *(const bf16x8*)(zr + (size_t)c * 8);
#pragma unroll
    for (int e = 0; e < 8; ++e) {
      float x = (float)v[e];
      float nm = fmaxf(m, x);
      s = s * __expf(m - nm) + __expf(x - nm);
      m = nm;
    }
  }
  if (t == 0) {
    float x = (float)zr[VV - 1];
    float nm = fmaxf(m, x);
    s = s * __expf(m - nm) + __expf(x - nm);
    m = nm;
  }
  for (int off = 32; off; off >>= 1) {
    float mo = __shfl_xor(m, off), so = __shfl_xor(s, off);
    float nm = fmaxf(m, mo);
    s = s * __expf(m - nm) + so * __expf(mo - nm);
    m = nm;
  }
  __shared__ float ms[8], ss[8];
  if ((t & 63) == 0) { ms[t >> 6] = m; ss[t >> 6] = s; }
  __syncthreads();
  if (t == 0) {
    float M = ms[0], S = ss[0];
    for (int wv = 1; wv < 8; ++wv) {
      float nm = fmaxf(M, ms[wv]);
      S = S * __expf(M - nm) + ss[wv] * __expf(ms[wv] - nm);
      M = nm;
    }
    ss[0] = logf(S) + M;  // lse
  }
  __syncthreads();
  const float lse = ss[0];
  float* orow = out + (size_t)b * VV;
  for (int v = t; v < VV; v += 512) orow[v] = (float)zr[v] - lse;
}

extern "C" void kernel_launch(void* const* d_in, const int* in_sizes, int n_in,
                              void* d_out, int out_size, void* d_ws, size_t ws_size,
                              hipStream_t stream) {
  const float* emb    = (const float*)d_in[0];
  const float* h0     = (const float*)d_in[1];
  const float* enc    = (const float*)d_in[2];
  const float* attn_W = (const float*)d_in[3];
  const float* attn_b = (const float*)d_in[4];
  const float* comb_W = (const float*)d_in[5];
  const float* comb_b = (const float*)d_in[6];
  const float* W_ih   = (const float*)d_in[7];
  const float* W_hh   = (const float*)d_in[8];
  const float* b_ih   = (const float*)d_in[9];
  const float* b_hh   = (const float*)d_in[10];
  const float* out_W  = (const float*)d_in[11];
  const float* out_b  = (const float*)d_in[12];

  float* out      = (float*)d_out;                 // B*V
  float* h1out    = out + (size_t)BB * VV;         // B*H
  float* attn_out = h1out + (size_t)BB * HH;       // B*L

  char* ws = (char*)d_ws;
  bf16* A_cat  = (bf16*)(ws);                      // 512 x 2048 (emb | attn_applied)
  bf16* cat2   = (bf16*)(ws + 2097152);            // 512 x 2048 (emb | h0)
  bf16* x      = (bf16*)(ws + 4194304);            // 512 x 1024
  bf16* h1b    = (bf16*)(ws + 5242880);            // 512 x 1024
  float* gi    = (float*)(ws + 6291456);           // 512 x 3072
  float* gh    = (float*)(ws + 12582912);          // 512 x 3072
  float* sp    = (float*)(ws + 18874368);          // 4 x 512 x 64 partials (512KB)
  bf16* aw_b   = (bf16*)(ws + 19398656);           // 512 x 64
  bf16* z      = (bf16*)(ws + 19464192);           // 512 x ZS

  k_convert<<<BB * HH / 256, 256, 0, stream>>>(emb, h0, A_cat, cat2);
  // scores: [emb|h0](512x2048) @ attn_W(2048x64), split-K=4 -> partials
  k_gemm<0, 0><<<dim3(2, 4), 256, 0, stream>>>(cat2, attn_W, nullptr, sp, LL, 512, LL, 2048);
  k_smax<<<BB / 4, 256, 0, stream>>>(sp, attn_b, attn_out, aw_b);
  // attn_applied: aw(512x64) @ enc(64x1024) -> A_cat[:,1024:]
  k_gemm<0, 2><<<dim3(32, 1), 256, 0, stream>>>(aw_b, enc, nullptr, A_cat + 1024, HH, LL, 2048, LL);
  // x = relu([emb|applied] @ comb_W + comb_b)
  k_gemm<0, 1><<<dim3(32, 1), 256, 0, stream>>>(A_cat, comb_W, comb_b, x, HH, 2 * HH, HH, 2 * HH);
  // gi = x @ W_ih^T + b_ih ; gh = h0 @ W_hh^T + b_hh
  k_gemm<1, 0><<<dim3(96, 1), 256, 0, stream>>>(x, W_ih, b_ih, gi, 3 * HH, HH, 3 * HH, HH);
  k_gemm<1, 0><<<dim3(96, 1), 256, 0, stream>>>(cat2 + 1024, W_hh, b_hh, gh, 3 * HH, HH, 3 * HH, 2048);
  k_gru<<<BB * HH / 256, 256, 0, stream>>>(gi, gh, h0, h1out, h1b);
  k_gemm<0, 2><<<dim3(2 * ((VV + 63) / 64), 1), 256, 0, stream>>>(h1b, out_W, out_b, z, VV, HH, ZS, HH);
  k_lsm<<<BB, 512, 0, stream>>>(z, out);
}

// Round 4
// 463.578 us; speedup vs baseline: 1.7909x; 1.0737x over previous
//
#include <hip/hip_runtime.h>

#define HH 1024
#define VV 50257
#define ZS 50264   // padded z row stride (mult of 8 -> 16B aligned rows)
#define NPAD 50304 // Wt rows (393 n-tiles * 128)
#define LL 64
#define BB 512

typedef __bf16 bf16;
typedef bf16 bf16x8 __attribute__((ext_vector_type(8)));
typedef float f32x4 __attribute__((ext_vector_type(4)));
typedef unsigned uint4v __attribute__((ext_vector_type(4)));

typedef __attribute__((address_space(1))) const unsigned int g_u32;
typedef __attribute__((address_space(3))) unsigned int l_u32;

static __device__ __forceinline__ bf16 f2bf(float f) {
  unsigned u = __builtin_bit_cast(unsigned, f);
  unsigned r = u + 0x7fffu + ((u >> 16) & 1u);
  unsigned short h = (unsigned short)(r >> 16);
  return __builtin_bit_cast(bf16, h);
}

static __device__ __forceinline__ unsigned cvt_pk(float lo, float hi) {
  unsigned r;
  asm("v_cvt_pk_bf16_f32 %0, %1, %2" : "=v"(r) : "v"(lo), "v"(hi));
  return r;
}

// ---------- transpose+convert out_W fp32[1024][50257] -> Wt bf16[50304][1024] ----------
__global__ __launch_bounds__(256) void k_tr(const float* __restrict__ W, bf16* __restrict__ Wt) {
  __shared__ float T[64][65];
  const int c0 = blockIdx.x * 64;   // output-row (vocab) tile
  const int k0 = blockIdx.y * 64;   // k tile
  const int t = threadIdx.x;
  const int cc = t & 63, k4 = t >> 6;
#pragma unroll 4
  for (int j = 0; j < 16; ++j) {
    const int k = k4 * 16 + j;
    const int c = c0 + cc;
    T[cc][k] = (c < VV) ? W[(size_t)(k0 + k) * VV + c] : 0.f;
  }
  __syncthreads();
  const int cc2 = t >> 3, k8 = (t & 7) * 8;
#pragma unroll
  for (int r = 0; r < 2; ++r) {
    const int row = cc2 + 32 * r;
    float v[8];
#pragma unroll
    for (int e = 0; e < 8; ++e) v[e] = T[row][k8 + e];
    uint4v p = {cvt_pk(v[0], v[1]), cvt_pk(v[2], v[3]), cvt_pk(v[4], v[5]), cvt_pk(v[6], v[7])};
    *(uint4v*)(Wt + (size_t)(c0 + row) * HH + k0 + k8) = p;
  }
}

// ---------- big GEMM (m97 structure): z = h1b(512x1024) @ Wt^T + out_b ----------
// 128x128 tile, BK=32, 4 waves (2x2, each 64x64), global_load_lds dwordx4 staging,
// double-buffered LDS, stage-before-compute + 1 barrier/iter, XCD swizzle m-innermost.
__global__ __launch_bounds__(256) void k_gemm_big(const bf16* __restrict__ A,
                                                  const bf16* __restrict__ Bt,
                                                  const float* __restrict__ bias,
                                                  bf16* __restrict__ C) {
  __shared__ __align__(16) bf16 Asm[2][4096];
  __shared__ __align__(16) bf16 Bsm[2][4096];
  const int t = threadIdx.x;
  const int bid = blockIdx.x;
  const int nwg = gridDim.x;  // 1572
  const int xcd = bid & 7, jj = bid >> 3;
  const int q = nwg >> 3, r = nwg & 7;
  const int w = (xcd < r ? xcd * (q + 1) : r * (q + 1) + (xcd - r) * q) + jj;
  const int m0 = (w & 3) * 128;   // m-innermost: 4 m-tiles per B panel adjacent
  const int n0 = (w >> 2) * 128;
  const int lane = t & 63, wv = t >> 6;
  const int wr = (wv & 1) * 64, wc = (wv >> 1) * 64;
  const int lg = lane >> 4, lr = lane & 15;

  // staging: wave wv owns chunks c0i, c0i+1 (16 rows each); lane l -> row +(l>>2), col (l&3)*8
  const int c0i = wv * 2;
  const int srow = c0i * 16 + (lane >> 2);
  const int skk = (lane & 3) * 8;
  const bf16* Ab0 = A + (size_t)(m0 + srow) * HH + skk;
  const bf16* Ab1 = Ab0 + (size_t)16 * HH;
  const bf16* Bb0 = Bt + (size_t)(n0 + srow) * HH + skk;
  const bf16* Bb1 = Bb0 + (size_t)16 * HH;

  f32x4 acc[4][4] = {};

  auto stage = [&](int buf, int koff) {
    __builtin_amdgcn_global_load_lds((g_u32*)(Ab0 + koff), (l_u32*)(&Asm[buf][c0i * 512]), 16, 0, 0);
    __builtin_amdgcn_global_load_lds((g_u32*)(Ab1 + koff), (l_u32*)(&Asm[buf][c0i * 512 + 512]), 16, 0, 0);
    __builtin_amdgcn_global_load_lds((g_u32*)(Bb0 + koff), (l_u32*)(&Bsm[buf][c0i * 512]), 16, 0, 0);
    __builtin_amdgcn_global_load_lds((g_u32*)(Bb1 + koff), (l_u32*)(&Bsm[buf][c0i * 512 + 512]), 16, 0, 0);
  };

  stage(0, 0);
  __syncthreads();
  int cur = 0;
  const int nk = HH / 32;  // 32
  for (int ik = 0; ik < nk; ++ik) {
    if (ik + 1 < nk) stage(cur ^ 1, (ik + 1) * 32);  // in flight during compute
    bf16x8 a[4], b[4];
#pragma unroll
    for (int i = 0; i < 4; ++i)
      a[i] = *(const bf16x8*)(&Asm[cur][(wr + 16 * i + lr) * 32 + lg * 8]);
#pragma unroll
    for (int j = 0; j < 4; ++j)
      b[j] = *(const bf16x8*)(&Bsm[cur][(wc + 16 * j + lr) * 32 + lg * 8]);
#pragma unroll
    for (int i = 0; i < 4; ++i)
#pragma unroll
      for (int j = 0; j < 4; ++j)
        acc[i][j] = __builtin_amdgcn_mfma_f32_16x16x32_bf16(a[i], b[j], acc[i][j], 0, 0, 0);
    __syncthreads();  // drains prefetch (vmcnt0) + protects buffer swap
    cur ^= 1;
  }

  float bb[4];
#pragma unroll
  for (int j = 0; j < 4; ++j) {
    const int col = n0 + wc + 16 * j + lr;
    bb[j] = (col < VV) ? bias[col] : 0.f;
  }
#pragma unroll
  for (int i = 0; i < 4; ++i)
#pragma unroll
    for (int j = 0; j < 4; ++j) {
      const int col = n0 + wc + 16 * j + lr;
      if (col < VV) {
#pragma unroll
        for (int rr = 0; rr < 4; ++rr) {
          const int row = m0 + wr + 16 * i + lg * 4 + rr;
          C[(size_t)row * ZS + col] = f2bf(acc[i][j][rr] + bb[j]);
        }
      }
    }
}

// ---------- convert: emb -> A_cat[:,0:1024]; emb,h0 -> cat2 ----------
__global__ void k_convert(const float* __restrict__ emb, const float* __restrict__ h0,
                          bf16* __restrict__ A_cat, bf16* __restrict__ cat2) {
  int i = blockIdx.x * 256 + threadIdx.x;  // < B*H
  int b = i >> 10, h = i & 1023;
  bf16 e = f2bf(emb[i]);
  A_cat[(size_t)b * 2048 + h] = e;
  cat2[(size_t)b * 2048 + h] = e;
  cat2[(size_t)b * 2048 + 1024 + h] = f2bf(h0[i]);
}

// ---------- generic small GEMM (round-3 proven) ----------
template <int BLAYOUT, int OMODE>
__global__ __launch_bounds__(256, 3) void k_gemm(
    const bf16* __restrict__ A, const float* __restrict__ Bm,
    const float* __restrict__ bias, void* __restrict__ Cout,
    int N, int K, int ldc, int lda) {
  __shared__ __align__(16) unsigned short Bs[2][64][40];
  const int t = threadIdx.x;
  const int nwg = gridDim.x;
  const int bid = blockIdx.x;
  const int kb = blockIdx.y;
  const int xcd = bid & 7, jj = bid >> 3;
  const int q = nwg >> 3, r = nwg & 7;
  const int w = (xcd < r ? xcd * (q + 1) : r * (q + 1) + (xcd - r) * q) + jj;
  const int n0 = (w >> 1) * 64;
  const int m0 = (w & 1) * 256;
  const int lane = t & 63, wv = t >> 6;
  const int lg = lane >> 4, lr = lane & 15;

  const bf16* Ap = A + (size_t)(m0 + wv * 64 + lr) * lda + (size_t)kb * K + lg * 8;
  const float* Bk = Bm + (BLAYOUT == 0 ? (size_t)kb * K * N : (size_t)0);

  const int sn0 = (BLAYOUT == 0) ? (t & 63) : (t >> 2);
  const int sk0 = (BLAYOUT == 0) ? ((t >> 6) * 8) : ((t & 3) * 8);

  f32x4 acc[4][4] = {};
  bf16x8 a[4], an[4];
#pragma unroll
  for (int i = 0; i < 4; ++i) a[i] = *(const bf16x8*)(Ap + (size_t)i * 16 * lda);

  const int nk = K >> 5;
  int cur = 0;

  {
    if (BLAYOUT == 0) {
      const bool nok = (n0 + sn0) < N;
      const float* bsrc = Bk + (size_t)sk0 * N + n0 + sn0;
      float v[8];
#pragma unroll
      for (int e = 0; e < 8; ++e) v[e] = nok ? bsrc[(size_t)e * N] : 0.f;
      uint4v p = {cvt_pk(v[0], v[1]), cvt_pk(v[2], v[3]), cvt_pk(v[4], v[5]), cvt_pk(v[6], v[7])};
      *(uint4v*)(&Bs[0][sn0][sk0]) = p;
    } else {
      const float* bsrc = Bk + (size_t)(n0 + sn0) * K + sk0;
      float4 f0 = *(const float4*)(bsrc);
      float4 f1 = *(const float4*)(bsrc + 4);
      uint4v p = {cvt_pk(f0.x, f0.y), cvt_pk(f0.z, f0.w), cvt_pk(f1.x, f1.y), cvt_pk(f1.z, f1.w)};
      *(uint4v*)(&Bs[0][sn0][sk0]) = p;
    }
  }

  for (int ik = 0; ik < nk; ++ik) {
    __syncthreads();
    const bool more = (ik + 1 < nk);
    if (more) {
      const int k0 = (ik + 1) * 32;
      if (BLAYOUT == 0) {
        const bool nok = (n0 + sn0) < N;
        const float* bsrc = Bk + (size_t)(k0 + sk0) * N + n0 + sn0;
        float v[8];
#pragma unroll
        for (int e = 0; e < 8; ++e) v[e] = nok ? bsrc[(size_t)e * N] : 0.f;
        uint4v p = {cvt_pk(v[0], v[1]), cvt_pk(v[2], v[3]), cvt_pk(v[4], v[5]), cvt_pk(v[6], v[7])};
        *(uint4v*)(&Bs[cur ^ 1][sn0][sk0]) = p;
      } else {
        const float* bsrc = Bk + (size_t)(n0 + sn0) * K + k0 + sk0;
        float4 f0 = *(const float4*)(bsrc);
        float4 f1 = *(const float4*)(bsrc + 4);
        uint4v p = {cvt_pk(f0.x, f0.y), cvt_pk(f0.z, f0.w), cvt_pk(f1.x, f1.y), cvt_pk(f1.z, f1.w)};
        *(uint4v*)(&Bs[cur ^ 1][sn0][sk0]) = p;
      }
#pragma unroll
      for (int i = 0; i < 4; ++i)
        an[i] = *(const bf16x8*)(Ap + (size_t)i * 16 * lda + (ik + 1) * 32);
    }
    bf16x8 b[4];
#pragma unroll
    for (int jx = 0; jx < 4; ++jx)
      b[jx] = *(const bf16x8*)(&Bs[cur][jx * 16 + lr][lg * 8]);
#pragma unroll
    for (int i = 0; i < 4; ++i)
#pragma unroll
      for (int jx = 0; jx < 4; ++jx)
        acc[i][jx] = __builtin_amdgcn_mfma_f32_16x16x32_bf16(a[i], b[jx], acc[i][jx], 0, 0, 0);
    if (more) {
#pragma unroll
      for (int i = 0; i < 4; ++i) a[i] = an[i];
    }
    cur ^= 1;
  }

  float bb[4];
#pragma unroll
  for (int jx = 0; jx < 4; ++jx) {
    int col = n0 + 16 * jx + lr;
    bb[jx] = (bias && col < N) ? bias[col] : 0.f;
  }
  float* co_f = (float*)Cout + (size_t)kb * BB * ldc;
  bf16* co_b = (bf16*)Cout;
#pragma unroll
  for (int i = 0; i < 4; ++i)
#pragma unroll
    for (int jx = 0; jx < 4; ++jx) {
      const int col = n0 + 16 * jx + lr;
      if (col < N) {
#pragma unroll
        for (int rr = 0; rr < 4; ++rr) {
          const int row = m0 + wv * 64 + 16 * i + lg * 4 + rr;
          float vvv = acc[i][jx][rr] + bb[jx];
          if (OMODE == 0)
            co_f[(size_t)row * ldc + col] = vvv;
          else if (OMODE == 1)
            co_b[(size_t)row * ldc + col] = f2bf(fmaxf(vvv, 0.f));
          else
            co_b[(size_t)row * ldc + col] = f2bf(vvv);
        }
      }
    }
}

// ---------- softmax over 64 scores/row ----------
__global__ __launch_bounds__(256) void k_smax(const float* __restrict__ sp,
                                              const float* __restrict__ attn_b,
                                              float* __restrict__ attn_out,
                                              bf16* __restrict__ aw_b) {
  const int t = threadIdx.x;
  const int row = blockIdx.x * 4 + (t >> 6);
  const int l = t & 63;
  const size_t idx = (size_t)row * LL + l;
  float s = sp[idx] + sp[idx + (size_t)BB * LL] + sp[idx + (size_t)2 * BB * LL] +
            sp[idx + (size_t)3 * BB * LL] + attn_b[l];
  float m = s;
#pragma unroll
  for (int off = 32; off; off >>= 1) m = fmaxf(m, __shfl_xor(m, off));
  float e = __expf(s - m);
  float sum = e;
#pragma unroll
  for (int off = 32; off; off >>= 1) sum += __shfl_xor(sum, off);
  float wv = e / sum;
  attn_out[idx] = wv;
  aw_b[idx] = f2bf(wv);
}

// ---------- GRU elementwise ----------
__global__ void k_gru(const float* __restrict__ gi, const float* __restrict__ gh,
                      const float* __restrict__ h0,
                      float* __restrict__ h1_out, bf16* __restrict__ h1b) {
  int i = blockIdx.x * 256 + threadIdx.x;  // B*H
  int b = i >> 10, h = i & 1023;
  size_t base = (size_t)b * 3072;
  float ir = gi[base + h], iz = gi[base + 1024 + h], in_ = gi[base + 2048 + h];
  float hr = gh[base + h], hz = gh[base + 1024 + h], hn = gh[base + 2048 + h];
  float r = 1.f / (1.f + __expf(-(ir + hr)));
  float z = 1.f / (1.f + __expf(-(iz + hz)));
  float n = tanhf(in_ + r * hn);
  float h1 = (1.f - z) * n + z * h0[i];
  h1_out[i] = h1;
  h1b[i] = f2bf(h1);
}

// ---------- log-softmax over padded z rows ----------
__global__ __launch_bounds__(512) void k_lsm(const bf16* __restrict__ z, float* __restrict__ out) {
  const int b = blockIdx.x, t = threadIdx.x;
  const bf16* zr = z + (size_t)b * ZS;
  float m = -1e30f, s = 0.f;
  for (int c = t; c < 6282; c += 512) {
    bf16x8 v = *(const bf16x8*)(zr + (size_t)c * 8);
#pragma unroll
    for (int e = 0; e < 8; ++e) {
      float x = (float)v[e];
      float nm = fmaxf(m, x);
      s = s * __expf(m - nm) + __expf(x - nm);
      m = nm;
    }
  }
  if (t == 0) {
    float x = (float)zr[VV - 1];
    float nm = fmaxf(m, x);
    s = s * __expf(m - nm) + __expf(x - nm);
    m = nm;
  }
  for (int off = 32; off; off >>= 1) {
    float mo = __shfl_xor(m, off), so = __shfl_xor(s, off);
    float nm = fmaxf(m, mo);
    s = s * __expf(m - nm) + so * __expf(mo - nm);
    m = nm;
  }
  __shared__ float ms[8], ss[8];
  if ((t & 63) == 0) { ms[t >> 6] = m; ss[t >> 6] = s; }
  __syncthreads();
  if (t == 0) {
    float M = ms[0], S = ss[0];
    for (int wv = 1; wv < 8; ++wv) {
      float nm = fmaxf(M, ms[wv]);
      S = S * __expf(M - nm) + ss[wv] * __expf(ms[wv] - nm);
      M = nm;
    }
    ss[0] = logf(S) + M;  // lse
  }
  __syncthreads();
  const float lse = ss[0];
  float* orow = out + (size_t)b * VV;
  for (int v = t; v < VV; v += 512) orow[v] = (float)zr[v] - lse;
}

extern "C" void kernel_launch(void* const* d_in, const int* in_sizes, int n_in,
                              void* d_out, int out_size, void* d_ws, size_t ws_size,
                              hipStream_t stream) {
  const float* emb    = (const float*)d_in[0];
  const float* h0     = (const float*)d_in[1];
  const float* enc    = (const float*)d_in[2];
  const float* attn_W = (const float*)d_in[3];
  const float* attn_b = (const float*)d_in[4];
  const float* comb_W = (const float*)d_in[5];
  const float* comb_b = (const float*)d_in[6];
  const float* W_ih   = (const float*)d_in[7];
  const float* W_hh   = (const float*)d_in[8];
  const float* b_ih   = (const float*)d_in[9];
  const float* b_hh   = (const float*)d_in[10];
  const float* out_W  = (const float*)d_in[11];
  const float* out_b  = (const float*)d_in[12];

  float* out      = (float*)d_out;                 // B*V
  float* h1out    = out + (size_t)BB * VV;         // B*H
  float* attn_out = h1out + (size_t)BB * HH;       // B*L

  char* ws = (char*)d_ws;
  bf16* A_cat  = (bf16*)(ws);                      // 512 x 2048 (emb | attn_applied)
  bf16* cat2   = (bf16*)(ws + 2097152);            // 512 x 2048 (emb | h0)
  bf16* x      = (bf16*)(ws + 4194304);            // 512 x 1024
  bf16* h1b    = (bf16*)(ws + 5242880);            // 512 x 1024
  float* gi    = (float*)(ws + 6291456);           // 512 x 3072
  float* gh    = (float*)(ws + 12582912);          // 512 x 3072
  float* sp    = (float*)(ws + 18874368);          // 4 x 512 x 64 partials
  bf16* aw_b   = (bf16*)(ws + 19398656);           // 512 x 64
  bf16* z      = (bf16*)(ws + 19464192);           // 512 x ZS
  bf16* Wt     = (bf16*)(ws + 70934528);           // 50304 x 1024 bf16 (103 MB)
  const size_t WS_NEED = 70934528ull + (size_t)NPAD * HH * 2;

  const bool bigpath = (ws_size >= WS_NEED);

  if (bigpath)
    k_tr<<<dim3(NPAD / 64, 16), 256, 0, stream>>>(out_W, Wt);
  k_convert<<<BB * HH / 256, 256, 0, stream>>>(emb, h0, A_cat, cat2);
  k_gemm<0, 0><<<dim3(2, 4), 256, 0, stream>>>(cat2, attn_W, nullptr, sp, LL, 512, LL, 2048);
  k_smax<<<BB / 4, 256, 0, stream>>>(sp, attn_b, attn_out, aw_b);
  k_gemm<0, 2><<<dim3(32, 1), 256, 0, stream>>>(aw_b, enc, nullptr, A_cat + 1024, HH, LL, 2048, LL);
  k_gemm<0, 1><<<dim3(32, 1), 256, 0, stream>>>(A_cat, comb_W, comb_b, x, HH, 2 * HH, HH, 2 * HH);
  k_gemm<1, 0><<<dim3(96, 1), 256, 0, stream>>>(x, W_ih, b_ih, gi, 3 * HH, HH, 3 * HH, HH);
  k_gemm<1, 0><<<dim3(96, 1), 256, 0, stream>>>(cat2 + 1024, W_hh, b_hh, gh, 3 * HH, HH, 3 * HH, 2048);
  k_gru<<<BB * HH / 256, 256, 0, stream>>>(gi, gh, h0, h1out, h1b);
  if (bigpath)
    k_gemm_big<<<dim3(4 * (NPAD / 128)), 256, 0, stream>>>(h1b, Wt, out_b, z);
  else
    k_gemm<0, 2><<<dim3(2 * ((VV + 63) / 64), 1), 256, 0, stream>>>(h1b, out_W, out_b, z, VV, HH, ZS, HH);
  k_lsm<<<BB, 512, 0, stream>>>(z, out);
}

// Round 5
// 438.155 us; speedup vs baseline: 1.8948x; 1.0580x over previous
//
#include <hip/hip_runtime.h>

#define HH 1024
#define VV 50257
#define ZS 50264    // padded z row stride (mult of 8 -> 16B aligned rows)
#define NPAD 50304  // Wt rows (393 n-tiles * 128)
#define NT 393      // n-tiles of big gemm
#define PLD 400     // partial row stride (pm/ps)
#define LL 64
#define BB 512
#define TRB 12576   // transpose blocks: 786 c-tiles * 16 k-tiles

typedef __bf16 bf16;
typedef bf16 bf16x8 __attribute__((ext_vector_type(8)));
typedef float f32x4 __attribute__((ext_vector_type(4)));
typedef unsigned uint4v __attribute__((ext_vector_type(4)));

typedef __attribute__((address_space(1))) const unsigned int g_u32;
typedef __attribute__((address_space(3))) unsigned int l_u32;

static __device__ __forceinline__ bf16 f2bf(float f) {
  unsigned u = __builtin_bit_cast(unsigned, f);
  unsigned r = u + 0x7fffu + ((u >> 16) & 1u);
  unsigned short h = (unsigned short)(r >> 16);
  return __builtin_bit_cast(bf16, h);
}

static __device__ __forceinline__ unsigned cvt_pk(float lo, float hi) {
  unsigned r;
  asm("v_cvt_pk_bf16_f32 %0, %1, %2" : "=v"(r) : "v"(lo), "v"(hi));
  return r;
}

// ================= device pieces =================

// transpose+convert one 64x64 tile of out_W fp32[1024][50257] -> Wt bf16[50304][1024]
static __device__ void dev_tr(char* smemraw, int tb, const float* __restrict__ W,
                              bf16* __restrict__ Wt) {
  float(*T)[65] = (float(*)[65])smemraw;
  const int ct = tb % 786, kt = tb / 786;
  const int c0 = ct * 64, k0 = kt * 64;
  const int t = threadIdx.x;
  const int cc = t & 63, k4 = t >> 6;
#pragma unroll 4
  for (int j = 0; j < 16; ++j) {
    const int k = k4 * 16 + j;
    const int c = c0 + cc;
    T[cc][k] = (c < VV) ? W[(size_t)(k0 + k) * VV + c] : 0.f;
  }
  __syncthreads();
  const int cc2 = t >> 3, k8 = (t & 7) * 8;
#pragma unroll
  for (int r = 0; r < 2; ++r) {
    const int row = cc2 + 32 * r;
    float v[8];
#pragma unroll
    for (int e = 0; e < 8; ++e) v[e] = T[row][k8 + e];
    uint4v p = {cvt_pk(v[0], v[1]), cvt_pk(v[2], v[3]), cvt_pk(v[4], v[5]), cvt_pk(v[6], v[7])};
    *(uint4v*)(Wt + (size_t)(c0 + row) * HH + k0 + k8) = p;
  }
}

// generic small GEMM: C(512 x N) = A(512 x K bf16, row stride lda) * B + bias
// BLAYOUT 0: B fp32 KxN n-contig; BLAYOUT 1: B fp32 NxK k-contig.
// OMODE 0: f32; 1: bf16 relu; 2: bf16. kb = bid / nwgx (split-K chunk).
template <int BLAYOUT, int OMODE>
static __device__ void dev_gemm(char* smemraw, int bid, int nwgx,
                                const bf16* __restrict__ A, const float* __restrict__ Bm,
                                const float* __restrict__ bias, void* __restrict__ Cout,
                                int N, int K, int ldc, int lda) {
  typedef unsigned short us40[64][40];
  us40* Bs = (us40*)smemraw;  // [2][64][40]
  const int t = threadIdx.x;
  const int kb = bid / nwgx;
  const int bidx = bid % nwgx;
  const int xcd = bidx & 7, jj = bidx >> 3;
  const int q = nwgx >> 3, r = nwgx & 7;
  const int w = (xcd < r ? xcd * (q + 1) : r * (q + 1) + (xcd - r) * q) + jj;
  const int n0 = (w >> 1) * 64;
  const int m0 = (w & 1) * 256;
  const int lane = t & 63, wv = t >> 6;
  const int lg = lane >> 4, lr = lane & 15;

  const bf16* Ap = A + (size_t)(m0 + wv * 64 + lr) * lda + (size_t)kb * K + lg * 8;
  const float* Bk = Bm + (BLAYOUT == 0 ? (size_t)kb * K * N : (size_t)0);

  const int sn0 = (BLAYOUT == 0) ? (t & 63) : (t >> 2);
  const int sk0 = (BLAYOUT == 0) ? ((t >> 6) * 8) : ((t & 3) * 8);

  f32x4 acc[4][4] = {};
  bf16x8 a[4], an[4];
#pragma unroll
  for (int i = 0; i < 4; ++i) a[i] = *(const bf16x8*)(Ap + (size_t)i * 16 * lda);

  const int nk = K >> 5;
  int cur = 0;

  {
    if (BLAYOUT == 0) {
      const bool nok = (n0 + sn0) < N;
      const float* bsrc = Bk + (size_t)sk0 * N + n0 + sn0;
      float v[8];
#pragma unroll
      for (int e = 0; e < 8; ++e) v[e] = nok ? bsrc[(size_t)e * N] : 0.f;
      uint4v p = {cvt_pk(v[0], v[1]), cvt_pk(v[2], v[3]), cvt_pk(v[4], v[5]), cvt_pk(v[6], v[7])};
      *(uint4v*)(&Bs[0][sn0][sk0]) = p;
    } else {
      const float* bsrc = Bk + (size_t)(n0 + sn0) * K + sk0;
      float4 f0 = *(const float4*)(bsrc);
      float4 f1 = *(const float4*)(bsrc + 4);
      uint4v p = {cvt_pk(f0.x, f0.y), cvt_pk(f0.z, f0.w), cvt_pk(f1.x, f1.y), cvt_pk(f1.z, f1.w)};
      *(uint4v*)(&Bs[0][sn0][sk0]) = p;
    }
  }

  for (int ik = 0; ik < nk; ++ik) {
    __syncthreads();
    const bool more = (ik + 1 < nk);
    if (more) {
      const int k0 = (ik + 1) * 32;
      if (BLAYOUT == 0) {
        const bool nok = (n0 + sn0) < N;
        const float* bsrc = Bk + (size_t)(k0 + sk0) * N + n0 + sn0;
        float v[8];
#pragma unroll
        for (int e = 0; e < 8; ++e) v[e] = nok ? bsrc[(size_t)e * N] : 0.f;
        uint4v p = {cvt_pk(v[0], v[1]), cvt_pk(v[2], v[3]), cvt_pk(v[4], v[5]), cvt_pk(v[6], v[7])};
        *(uint4v*)(&Bs[cur ^ 1][sn0][sk0]) = p;
      } else {
        const float* bsrc = Bk + (size_t)(n0 + sn0) * K + k0 + sk0;
        float4 f0 = *(const float4*)(bsrc);
        float4 f1 = *(const float4*)(bsrc + 4);
        uint4v p = {cvt_pk(f0.x, f0.y), cvt_pk(f0.z, f0.w), cvt_pk(f1.x, f1.y), cvt_pk(f1.z, f1.w)};
        *(uint4v*)(&Bs[cur ^ 1][sn0][sk0]) = p;
      }
#pragma unroll
      for (int i = 0; i < 4; ++i)
        an[i] = *(const bf16x8*)(Ap + (size_t)i * 16 * lda + (ik + 1) * 32);
    }
    bf16x8 b[4];
#pragma unroll
    for (int jx = 0; jx < 4; ++jx)
      b[jx] = *(const bf16x8*)(&Bs[cur][jx * 16 + lr][lg * 8]);
#pragma unroll
    for (int i = 0; i < 4; ++i)
#pragma unroll
      for (int jx = 0; jx < 4; ++jx)
        acc[i][jx] = __builtin_amdgcn_mfma_f32_16x16x32_bf16(a[i], b[jx], acc[i][jx], 0, 0, 0);
    if (more) {
#pragma unroll
      for (int i = 0; i < 4; ++i) a[i] = an[i];
    }
    cur ^= 1;
  }

  float bb[4];
#pragma unroll
  for (int jx = 0; jx < 4; ++jx) {
    int col = n0 + 16 * jx + lr;
    bb[jx] = (bias && col < N) ? bias[col] : 0.f;
  }
  float* co_f = (float*)Cout + (size_t)kb * BB * ldc;
  bf16* co_b = (bf16*)Cout;
#pragma unroll
  for (int i = 0; i < 4; ++i)
#pragma unroll
    for (int jx = 0; jx < 4; ++jx) {
      const int col = n0 + 16 * jx + lr;
      if (col < N) {
#pragma unroll
        for (int rr = 0; rr < 4; ++rr) {
          const int row = m0 + wv * 64 + 16 * i + lg * 4 + rr;
          float vvv = acc[i][jx][rr] + bb[jx];
          if (OMODE == 0)
            co_f[(size_t)row * ldc + col] = vvv;
          else if (OMODE == 1)
            co_b[(size_t)row * ldc + col] = f2bf(fmaxf(vvv, 0.f));
          else
            co_b[(size_t)row * ldc + col] = f2bf(vvv);
        }
      }
    }
}

static __device__ void dev_convert(int bid, const float* __restrict__ emb,
                                   const float* __restrict__ h0, bf16* __restrict__ A_cat,
                                   bf16* __restrict__ cat2) {
  int i = bid * 256 + threadIdx.x;
  int b = i >> 10, h = i & 1023;
  bf16 e = f2bf(emb[i]);
  A_cat[(size_t)b * 2048 + h] = e;
  cat2[(size_t)b * 2048 + h] = e;
  cat2[(size_t)b * 2048 + 1024 + h] = f2bf(h0[i]);
}

static __device__ void dev_smax(int bid, const float* __restrict__ sp,
                                const float* __restrict__ attn_b, float* __restrict__ attn_out,
                                bf16* __restrict__ aw_b) {
  const int t = threadIdx.x;
  const int row = bid * 4 + (t >> 6);
  const int l = t & 63;
  const size_t idx = (size_t)row * LL + l;
  float s = sp[idx] + sp[idx + (size_t)BB * LL] + sp[idx + (size_t)2 * BB * LL] +
            sp[idx + (size_t)3 * BB * LL] + attn_b[l];
  float m = s;
#pragma unroll
  for (int off = 32; off; off >>= 1) m = fmaxf(m, __shfl_xor(m, off));
  float e = __expf(s - m);
  float sum = e;
#pragma unroll
  for (int off = 32; off; off >>= 1) sum += __shfl_xor(sum, off);
  float wv = e / sum;
  attn_out[idx] = wv;
  aw_b[idx] = f2bf(wv);
}

static __device__ void dev_gru(int bid, const float* __restrict__ gi, const float* __restrict__ gh,
                               const float* __restrict__ h0, float* __restrict__ h1_out,
                               bf16* __restrict__ h1b) {
  int i = bid * 256 + threadIdx.x;
  int b = i >> 10, h = i & 1023;
  size_t base = (size_t)b * 3072;
  float ir = gi[base + h], iz = gi[base + 1024 + h], in_ = gi[base + 2048 + h];
  float hr = gh[base + h], hz = gh[base + 1024 + h], hn = gh[base + 2048 + h];
  float r = 1.f / (1.f + __expf(-(ir + hr)));
  float z = 1.f / (1.f + __expf(-(iz + hz)));
  float n = tanhf(in_ + r * hn);
  float h1 = (1.f - z) * n + z * h0[i];
  h1_out[i] = h1;
  h1b[i] = f2bf(h1);
}

// ================= fat kernels: chain work + transpose slices =================

__global__ __launch_bounds__(256) void k_fat_convert(const float* emb, const float* h0,
                                                     bf16* A_cat, bf16* cat2, const float* W,
                                                     bf16* Wt, int trOff) {
  __shared__ __align__(16) char sm[16640];
  const int bid = blockIdx.x;
  if (bid < 2048) dev_convert(bid, emb, h0, A_cat, cat2);
  else { int tb = trOff + bid - 2048; if (tb < TRB) dev_tr(sm, tb, W, Wt); }
}

__global__ __launch_bounds__(256, 3) void k_fat_score(const bf16* cat2, const float* attn_W,
                                                      float* sp, const float* W, bf16* Wt,
                                                      int trOff) {
  __shared__ __align__(16) char sm[16640];
  const int bid = blockIdx.x;
  if (bid < 8) dev_gemm<0, 0>(sm, bid, 2, cat2, attn_W, nullptr, sp, LL, 512, LL, 2048);
  else { int tb = trOff + bid - 8; if (tb < TRB) dev_tr(sm, tb, W, Wt); }
}

__global__ __launch_bounds__(256) void k_fat_smax(const float* sp, const float* attn_b,
                                                  float* attn_out, bf16* aw_b, const float* W,
                                                  bf16* Wt, int trOff) {
  __shared__ __align__(16) char sm[16640];
  const int bid = blockIdx.x;
  if (bid < 128) dev_smax(bid, sp, attn_b, attn_out, aw_b);
  else { int tb = trOff + bid - 128; if (tb < TRB) dev_tr(sm, tb, W, Wt); }
}

__global__ __launch_bounds__(256, 3) void k_fat_apgh(const bf16* aw_b, const float* enc,
                                                     bf16* A_cat, const bf16* cat2,
                                                     const float* W_hh, const float* b_hh,
                                                     float* gh, const float* W, bf16* Wt,
                                                     int trOff) {
  __shared__ __align__(16) char sm[16640];
  const int bid = blockIdx.x;
  if (bid < 32)
    dev_gemm<0, 2>(sm, bid, 32, aw_b, enc, nullptr, A_cat + 1024, HH, LL, 2048, LL);
  else if (bid < 128)
    dev_gemm<1, 0>(sm, bid - 32, 96, cat2 + 1024, W_hh, b_hh, gh, 3 * HH, HH, 3 * HH, 2048);
  else { int tb = trOff + bid - 128; if (tb < TRB) dev_tr(sm, tb, W, Wt); }
}

__global__ __launch_bounds__(256, 3) void k_fat_comb(const bf16* A_cat, const float* comb_W,
                                                     const float* comb_b, bf16* x, const float* W,
                                                     bf16* Wt, int trOff) {
  __shared__ __align__(16) char sm[16640];
  const int bid = blockIdx.x;
  if (bid < 32) dev_gemm<0, 1>(sm, bid, 32, A_cat, comb_W, comb_b, x, HH, 2 * HH, HH, 2 * HH);
  else { int tb = trOff + bid - 32; if (tb < TRB) dev_tr(sm, tb, W, Wt); }
}

__global__ __launch_bounds__(256, 3) void k_fat_gi(const bf16* x, const float* W_ih,
                                                   const float* b_ih, float* gi, const float* W,
                                                   bf16* Wt, int trOff) {
  __shared__ __align__(16) char sm[16640];
  const int bid = blockIdx.x;
  if (bid < 96) dev_gemm<1, 0>(sm, bid, 96, x, W_ih, b_ih, gi, 3 * HH, HH, 3 * HH, HH);
  else { int tb = trOff + bid - 96; if (tb < TRB) dev_tr(sm, tb, W, Wt); }
}

__global__ __launch_bounds__(256) void k_fat_gru(const float* gi, const float* gh, const float* h0,
                                                 float* h1_out, bf16* h1b, const float* W,
                                                 bf16* Wt, int trOff) {
  __shared__ __align__(16) char sm[16640];
  const int bid = blockIdx.x;
  if (bid < 2048) dev_gru(bid, gi, gh, h0, h1_out, h1b);
  else { int tb = trOff + bid - 2048; if (tb < TRB) dev_tr(sm, tb, W, Wt); }
}

// ================= big GEMM with fused log-softmax partials =================

__global__ __launch_bounds__(256) void k_gemm_big(const bf16* __restrict__ A,
                                                  const bf16* __restrict__ Bt,
                                                  const float* __restrict__ bias,
                                                  bf16* __restrict__ C,
                                                  float* __restrict__ pm,
                                                  float* __restrict__ ps) {
  __shared__ __align__(16) bf16 Asm[2][4096];
  __shared__ __align__(16) bf16 Bsm[2][4096];
  __shared__ float sm_m[2][128], sm_s[2][128];
  const int t = threadIdx.x;
  const int bid = blockIdx.x;
  const int nwg = gridDim.x;  // 1572
  const int xcd = bid & 7, jj = bid >> 3;
  const int q = nwg >> 3, r = nwg & 7;
  const int w = (xcd < r ? xcd * (q + 1) : r * (q + 1) + (xcd - r) * q) + jj;
  const int m0 = (w & 3) * 128;
  const int n0 = (w >> 2) * 128;
  const int lane = t & 63, wv = t >> 6;
  const int wr = (wv & 1) * 64, wc = (wv >> 1) * 64;
  const int lg = lane >> 4, lr = lane & 15;

  const int c0i = wv * 2;
  const int srow = c0i * 16 + (lane >> 2);
  const int skk = (lane & 3) * 8;
  const bf16* Ab0 = A + (size_t)(m0 + srow) * HH + skk;
  const bf16* Ab1 = Ab0 + (size_t)16 * HH;
  const bf16* Bb0 = Bt + (size_t)(n0 + srow) * HH + skk;
  const bf16* Bb1 = Bb0 + (size_t)16 * HH;

  f32x4 acc[4][4] = {};

  auto stage = [&](int buf, int koff) {
    __builtin_amdgcn_global_load_lds((g_u32*)(Ab0 + koff), (l_u32*)(&Asm[buf][c0i * 512]), 16, 0, 0);
    __builtin_amdgcn_global_load_lds((g_u32*)(Ab1 + koff), (l_u32*)(&Asm[buf][c0i * 512 + 512]), 16, 0, 0);
    __builtin_amdgcn_global_load_lds((g_u32*)(Bb0 + koff), (l_u32*)(&Bsm[buf][c0i * 512]), 16, 0, 0);
    __builtin_amdgcn_global_load_lds((g_u32*)(Bb1 + koff), (l_u32*)(&Bsm[buf][c0i * 512 + 512]), 16, 0, 0);
  };

  stage(0, 0);
  __syncthreads();
  int cur = 0;
  const int nk = HH / 32;
  for (int ik = 0; ik < nk; ++ik) {
    if (ik + 1 < nk) stage(cur ^ 1, (ik + 1) * 32);
    bf16x8 a[4], b[4];
#pragma unroll
    for (int i = 0; i < 4; ++i)
      a[i] = *(const bf16x8*)(&Asm[cur][(wr + 16 * i + lr) * 32 + lg * 8]);
#pragma unroll
    for (int j = 0; j < 4; ++j)
      b[j] = *(const bf16x8*)(&Bsm[cur][(wc + 16 * j + lr) * 32 + lg * 8]);
#pragma unroll
    for (int i = 0; i < 4; ++i)
#pragma unroll
      for (int j = 0; j < 4; ++j)
        acc[i][j] = __builtin_amdgcn_mfma_f32_16x16x32_bf16(a[i], b[j], acc[i][j], 0, 0, 0);
    __syncthreads();
    cur ^= 1;
  }

  // fold bias into acc
  float bb[4];
#pragma unroll
  for (int j = 0; j < 4; ++j) {
    const int col = n0 + wc + 16 * j + lr;
    bb[j] = (col < VV) ? bias[col] : 0.f;
  }
#pragma unroll
  for (int i = 0; i < 4; ++i)
#pragma unroll
    for (int j = 0; j < 4; ++j)
#pragma unroll
      for (int rr = 0; rr < 4; ++rr) acc[i][j][rr] += bb[j];

  // store z
#pragma unroll
  for (int i = 0; i < 4; ++i)
#pragma unroll
    for (int j = 0; j < 4; ++j) {
      const int col = n0 + wc + 16 * j + lr;
      if (col < VV) {
#pragma unroll
        for (int rr = 0; rr < 4; ++rr) {
          const int row = m0 + wr + 16 * i + lg * 4 + rr;
          C[(size_t)row * ZS + col] = f2bf(acc[i][j][rr]);
        }
      }
    }

  // per-row (max, sumexp) partials over this block's 128 cols
#pragma unroll
  for (int i = 0; i < 4; ++i)
#pragma unroll
    for (int rr = 0; rr < 4; ++rr) {
      float mr = -1e30f;
#pragma unroll
      for (int j = 0; j < 4; ++j)
        if (n0 + wc + 16 * j + lr < VV) mr = fmaxf(mr, acc[i][j][rr]);
      float sr = 0.f;
#pragma unroll
      for (int j = 0; j < 4; ++j)
        if (n0 + wc + 16 * j + lr < VV) sr += __expf(acc[i][j][rr] - mr);
#pragma unroll
      for (int off = 1; off < 16; off <<= 1) {
        float mo = __shfl_xor(mr, off), so = __shfl_xor(sr, off);
        float nm = fmaxf(mr, mo);
        sr = sr * __expf(mr - nm) + so * __expf(mo - nm);
        mr = nm;
      }
      if (lr == 0) {
        const int row = wr + 16 * i + lg * 4 + rr;
        sm_m[wc >> 6][row] = mr;
        sm_s[wc >> 6][row] = sr;
      }
    }
  __syncthreads();
  if (t < 128) {
    float m0v = sm_m[0][t], s0v = sm_s[0][t];
    float m1v = sm_m[1][t], s1v = sm_s[1][t];
    float nm = fmaxf(m0v, m1v);
    float sv = s0v * __expf(m0v - nm) + s1v * __expf(m1v - nm);
    const int grow = m0 + t;
    pm[(size_t)grow * PLD + (n0 >> 7)] = nm;
    ps[(size_t)grow * PLD + (n0 >> 7)] = sv;
  }
}

// ================= lse reduce + final subtract =================

__global__ __launch_bounds__(256) void k_lse(const float* __restrict__ pm,
                                             const float* __restrict__ ps,
                                             float* __restrict__ lse) {
  const int row = blockIdx.x * 4 + (threadIdx.x >> 6);
  const int l = threadIdx.x & 63;
  float m = -1e30f, s = 0.f;
  for (int tt = l; tt < NT; tt += 64) {
    float mo = pm[(size_t)row * PLD + tt], so = ps[(size_t)row * PLD + tt];
    float nm = fmaxf(m, mo);
    s = s * __expf(m - nm) + so * __expf(mo - nm);
    m = nm;
  }
#pragma unroll
  for (int off = 32; off; off >>= 1) {
    float mo = __shfl_xor(m, off), so = __shfl_xor(s, off);
    float nm = fmaxf(m, mo);
    s = s * __expf(m - nm) + so * __expf(mo - nm);
    m = nm;
  }
  if (l == 0) lse[row] = logf(s) + m;
}

__global__ __launch_bounds__(256) void k_out(const bf16* __restrict__ z,
                                             const float* __restrict__ lse,
                                             float* __restrict__ out) {
  const int b = blockIdx.y;
  const int c0 = blockIdx.x * 4096 + threadIdx.x * 16;
  const float l = lse[b];
  const bf16* zr = z + (size_t)b * ZS;
  float* orow = out + (size_t)b * VV;
  if (c0 + 16 <= VV) {
    bf16x8 v0 = *(const bf16x8*)(zr + c0);
    bf16x8 v1 = *(const bf16x8*)(zr + c0 + 8);
#pragma unroll
    for (int e = 0; e < 8; ++e) orow[c0 + e] = (float)v0[e] - l;
#pragma unroll
    for (int e = 0; e < 8; ++e) orow[c0 + 8 + e] = (float)v1[e] - l;
  } else if (c0 < VV) {
    for (int e = 0; e < VV - c0; ++e) orow[c0 + e] = (float)zr[c0 + e] - l;
  }
}

// ================= fallback (small ws): standalone kernels =================

template <int BLAYOUT, int OMODE>
__global__ __launch_bounds__(256, 3) void k_gemm(const bf16* A, const float* Bm, const float* bias,
                                                 void* Cout, int N, int K, int ldc, int lda) {
  __shared__ __align__(16) char sm[10240];
  dev_gemm<BLAYOUT, OMODE>(sm, blockIdx.y * gridDim.x + blockIdx.x, gridDim.x, A, Bm, bias, Cout,
                           N, K, ldc, lda);
}

__global__ __launch_bounds__(512) void k_lsm(const bf16* __restrict__ z, float* __restrict__ out) {
  const int b = blockIdx.x, t = threadIdx.x;
  const bf16* zr = z + (size_t)b * ZS;
  float m = -1e30f, s = 0.f;
  for (int c = t; c < 6282; c += 512) {
    bf16x8 v = *(const bf16x8*)(zr + (size_t)c * 8);
#pragma unroll
    for (int e = 0; e < 8; ++e) {
      float x = (float)v[e];
      float nm = fmaxf(m, x);
      s = s * __expf(m - nm) + __expf(x - nm);
      m = nm;
    }
  }
  if (t == 0) {
    float x = (float)zr[VV - 1];
    float nm = fmaxf(m, x);
    s = s * __expf(m - nm) + __expf(x - nm);
    m = nm;
  }
  for (int off = 32; off; off >>= 1) {
    float mo = __shfl_xor(m, off), so = __shfl_xor(s, off);
    float nm = fmaxf(m, mo);
    s = s * __expf(m - nm) + so * __expf(mo - nm);
    m = nm;
  }
  __shared__ float ms[8], ss[8];
  if ((t & 63) == 0) { ms[t >> 6] = m; ss[t >> 6] = s; }
  __syncthreads();
  if (t == 0) {
    float M = ms[0], S = ss[0];
    for (int wv = 1; wv < 8; ++wv) {
      float nm = fmaxf(M, ms[wv]);
      S = S * __expf(M - nm) + ss[wv] * __expf(ms[wv] - nm);
      M = nm;
    }
    ss[0] = logf(S) + M;
  }
  __syncthreads();
  const float lse = ss[0];
  float* orow = out + (size_t)b * VV;
  for (int v = t; v < VV; v += 512) orow[v] = (float)zr[v] - lse;
}

__global__ void k_convertG(const float* emb, const float* h0, bf16* A_cat, bf16* cat2) {
  dev_convert(blockIdx.x, emb, h0, A_cat, cat2);
}
__global__ void k_smaxG(const float* sp, const float* attn_b, float* attn_out, bf16* aw_b) {
  dev_smax(blockIdx.x, sp, attn_b, attn_out, aw_b);
}
__global__ void k_gruG(const float* gi, const float* gh, const float* h0, float* h1_out,
                       bf16* h1b) {
  dev_gru(blockIdx.x, gi, gh, h0, h1_out, h1b);
}

// ================= host =================

extern "C" void kernel_launch(void* const* d_in, const int* in_sizes, int n_in,
                              void* d_out, int out_size, void* d_ws, size_t ws_size,
                              hipStream_t stream) {
  const float* emb    = (const float*)d_in[0];
  const float* h0     = (const float*)d_in[1];
  const float* enc    = (const float*)d_in[2];
  const float* attn_W = (const float*)d_in[3];
  const float* attn_b = (const float*)d_in[4];
  const float* comb_W = (const float*)d_in[5];
  const float* comb_b = (const float*)d_in[6];
  const float* W_ih   = (const float*)d_in[7];
  const float* W_hh   = (const float*)d_in[8];
  const float* b_ih   = (const float*)d_in[9];
  const float* b_hh   = (const float*)d_in[10];
  const float* out_W  = (const float*)d_in[11];
  const float* out_b  = (const float*)d_in[12];

  float* out      = (float*)d_out;
  float* h1out    = out + (size_t)BB * VV;
  float* attn_out = h1out + (size_t)BB * HH;

  char* ws = (char*)d_ws;
  bf16* A_cat  = (bf16*)(ws);
  bf16* cat2   = (bf16*)(ws + 2097152);
  bf16* x      = (bf16*)(ws + 4194304);
  bf16* h1b    = (bf16*)(ws + 5242880);
  float* gi    = (float*)(ws + 6291456);
  float* gh    = (float*)(ws + 12582912);
  float* sp    = (float*)(ws + 18874368);
  bf16* aw_b   = (bf16*)(ws + 19398656);
  bf16* z      = (bf16*)(ws + 19464192);
  bf16* Wt     = (bf16*)(ws + 70934528);                 // 50304 x 1024 bf16 (103 MB)
  float* pm    = (float*)(ws + 173957120);               // 512 x 400
  float* ps    = (float*)(ws + 174776320);               // 512 x 400
  float* lseb  = (float*)(ws + 175595520);               // 512
  const size_t WS_NEED = 175597568ull;

  if (ws_size >= WS_NEED) {
    // slice the transpose (TRB blocks) across the 7 chain launches
    const int SL = 1797;
    int off = 0;
    k_fat_convert<<<2048 + SL, 256, 0, stream>>>(emb, h0, A_cat, cat2, out_W, Wt, off); off += SL;
    k_fat_score<<<8 + SL, 256, 0, stream>>>(cat2, attn_W, sp, out_W, Wt, off); off += SL;
    k_fat_smax<<<128 + SL, 256, 0, stream>>>(sp, attn_b, attn_out, aw_b, out_W, Wt, off); off += SL;
    k_fat_apgh<<<128 + SL, 256, 0, stream>>>(aw_b, enc, A_cat, cat2, W_hh, b_hh, gh, out_W, Wt, off); off += SL;
    k_fat_comb<<<32 + SL, 256, 0, stream>>>(A_cat, comb_W, comb_b, x, out_W, Wt, off); off += SL;
    k_fat_gi<<<96 + SL, 256, 0, stream>>>(x, W_ih, b_ih, gi, out_W, Wt, off); off += SL;
    k_fat_gru<<<2048 + (TRB - off), 256, 0, stream>>>(gi, gh, h0, h1out, h1b, out_W, Wt, off);
    k_gemm_big<<<4 * (NPAD / 128), 256, 0, stream>>>(h1b, Wt, out_b, z, pm, ps);
    k_lse<<<BB / 4, 256, 0, stream>>>(pm, ps, lseb);
    k_out<<<dim3(13, BB), 256, 0, stream>>>(z, lseb, out);
  } else {
    k_convertG<<<BB * HH / 256, 256, 0, stream>>>(emb, h0, A_cat, cat2);
    k_gemm<0, 0><<<dim3(2, 4), 256, 0, stream>>>(cat2, attn_W, nullptr, sp, LL, 512, LL, 2048);
    k_smaxG<<<BB / 4, 256, 0, stream>>>(sp, attn_b, attn_out, aw_b);
    k_gemm<0, 2><<<dim3(32, 1), 256, 0, stream>>>(aw_b, enc, nullptr, A_cat + 1024, HH, LL, 2048, LL);
    k_gemm<0, 1><<<dim3(32, 1), 256, 0, stream>>>(A_cat, comb_W, comb_b, x, HH, 2 * HH, HH, 2 * HH);
    k_gemm<1, 0><<<dim3(96, 1), 256, 0, stream>>>(x, W_ih, b_ih, gi, 3 * HH, HH, 3 * HH, HH);
    k_gemm<1, 0><<<dim3(96, 1), 256, 0, stream>>>(cat2 + 1024, W_hh, b_hh, gh, 3 * HH, HH, 3 * HH, 2048);
    k_gruG<<<BB * HH / 256, 256, 0, stream>>>(gi, gh, h0, h1out, h1b);
    k_gemm<0, 2><<<dim3(2 * ((VV + 63) / 64), 1), 256, 0, stream>>>(h1b, out_W, out_b, z, VV, HH, ZS, HH);
    k_lsm<<<BB, 512, 0, stream>>>(z, out);
  }
}